// Round 11
// baseline (144.924 us; speedup 1.0000x reference)
//
#include <hip/hip_runtime.h>
#include <stdint.h>

typedef __attribute__((ext_vector_type(8))) __bf16 bf16x8;
typedef __attribute__((ext_vector_type(4))) float f32x4;
typedef __attribute__((ext_vector_type(8))) unsigned short us8;

__device__ __forceinline__ unsigned short f2bf(float f) {
  union { float f; unsigned int u; } v; v.f = f;
  unsigned int u = v.u;
  u = (u + 0x7FFFu + ((u >> 16) & 1u)) >> 16;   // RNE
  return (unsigned short)u;
}
__device__ __forceinline__ float bf2f(unsigned int u) {
  union { unsigned int u; float f; } v; v.u = u << 16;
  return v.f;
}

// ---------------------------------------------------------------------------
// Kernel 1: transpose + bf16-convert the three DxD weight matrices into one
// concatenated B' (3072 x 1024): Wt3[mat*1024 + n][k] = (bf16) W_mat[k][n].
// ---------------------------------------------------------------------------
__global__ __launch_bounds__(256) void wconv(
    const float* __restrict__ Wa, const float* __restrict__ Wsh,
    const float* __restrict__ Wsc, unsigned short* __restrict__ Wt3)
{
  const float* W;
  if (blockIdx.z == 0)      W = Wa;
  else if (blockIdx.z == 1) W = Wsh;
  else                      W = Wsc;
  unsigned short* O = Wt3 + (size_t)blockIdx.z * 1024 * 1024;
  const int k0 = blockIdx.x * 64;
  const int n0 = blockIdx.y * 64;
  __shared__ float t[64][65];
  const int r = threadIdx.x >> 4;
  const int c4 = threadIdx.x & 15;
#pragma unroll
  for (int i = 0; i < 4; ++i) {
    const int row = r + i * 16;
    const float4 v = *(const float4*)(W + (size_t)(k0 + row) * 1024 + n0 + c4 * 4);
    t[row][c4 * 4 + 0] = v.x; t[row][c4 * 4 + 1] = v.y;
    t[row][c4 * 4 + 2] = v.z; t[row][c4 * 4 + 3] = v.w;
  }
  __syncthreads();
#pragma unroll
  for (int i = 0; i < 4; ++i) {
    const int nr = r + i * 16;
    ushort4 o;
    o.x = f2bf(t[c4 * 4 + 0][nr]);
    o.y = f2bf(t[c4 * 4 + 1][nr]);
    o.z = f2bf(t[c4 * 4 + 2][nr]);
    o.w = f2bf(t[c4 * 4 + 3][nr]);
    *(ushort4*)(O + (size_t)(n0 + nr) * 1024 + k0 + c4 * 4) = o;
  }
}

// ---------------------------------------------------------------------------
// Kernel 2: ONE GEMM  C'[8192 x 3072] = x @ concat(Wa^T|Wsh^T|Wsc^T)^T.
// R10 post-mortem: coarse phase-split + sched_barrier(0) pinning = m196/m141
// anti-pattern (13% MfmaUtil). The 2-barrier drain family caps ~600 TF
// (m230/m233); the measured escape at EXACTLY our regime (256^2, K=1024) is
// m248's fine-interleaved phases + counted waits: 848 TF.
// R11: BM=256 BN=192 BK=64, grid 32x16=512 (= 2 full rounds/CU, no tail),
// 8 waves 2Mx4N (wave 128x48, acc 96 regs). Per K-iter, 4 phases of
// {2 A-frag ds_reads -> 12 MFMA}; next-tile A loads + B gload_lds issued at
// P0 (A first so compiler xv-waits never drain B), T14 write-late cvt+
// ds_write at P2/P3 into the other buffer. ONE barrier per iter:
// lgkm(0)+vmcnt(0)+s_barrier (B has ~4 phases of flight by then).
// No sched_barrier pinning; compiler manages all lgkm fine-grained waits.
// Swizzle swz(row)=(row&7)<<4 on gload_lds SOURCE + ds_write + ds_read.
// ---------------------------------------------------------------------------
__global__ __launch_bounds__(512, 2) void gemm3(
    const float* __restrict__ x, const unsigned short* __restrict__ Wt3,
    const float* __restrict__ ba,
    unsigned short* __restrict__ ya, unsigned short* __restrict__ pk16)
{
  __shared__ unsigned short sX[2][256 * 64];   // 2 x 32 KB
  __shared__ unsigned short sB[2][192 * 64];   // 2 x 24 KB  -> 112 KB total

  const int tid = threadIdx.x;
  const int lane = tid & 63;
  const int wid = tid >> 6;      // 0..7
  const int wm = wid >> 2;       // 0..1  (M half: 128 rows)
  const int wn = wid & 3;        // 0..3  (N quarter: 48 cols)

  // 512 blocks = 32 M-tiles x 16 N-tiles. XCD-ownership remap (R7-proven:
  // FETCH 137->44MB): xcd owns M-slabs {xcd, xcd+8, xcd+16, xcd+24}.
  const int bid = blockIdx.x;
  const int xcd = bid & 7;
  const int r   = bid >> 3;          // 0..63
  const int ntl = r & 15;            // N tile
  const int mg  = r >> 4;            // M group 0..3
  const int bm0 = (xcd + (mg << 3)) * 256;
  const int bn0 = ntl * 192;

  // --- B staging map (gload_lds; swizzle via pre-swizzled SOURCE, rule #21)
  int rowS[3], colS[3];
#pragma unroll
  for (int p = 0; p < 3; ++p) {
    const int po = (p * 512 + tid) * 16;      // phys byte in 24 KB tile
    const int rr = po >> 7;                   // 128 B per row (64 bf16)
    const int lo = po ^ ((rr & 7) << 4);
    rowS[p] = rr;                             // 0..191
    colS[p] = (lo & 127) >> 1;                // bf16 col
  }

  // --- A staging map: half h covers rows [h*128,h*128+128); 4 thr/row,
  // 16 f32 (64 B) per thread -> cvt -> two 16 B swizzled ds_writes.
  const int ar  = tid >> 2;          // 0..127 row in half
  const int acf = (tid & 3) * 16;    // f32 col base
  const int acb = acf * 2;           // bf16 byte col (0..96)
  const int asw = (ar & 7) << 4;     // swizzle XOR (row&7 invariant per thr)

  const int lr = lane & 15;
  const int lk = lane >> 4;

  f32x4 acc[8][3];                   // 96 regs
  const f32x4 z = {0.f, 0.f, 0.f, 0.f};
#pragma unroll
  for (int m = 0; m < 8; ++m)
#pragma unroll
    for (int j = 0; j < 3; ++j) acc[m][j] = z;

  auto stageB = [&](int k0, int buf) {
#pragma unroll
    for (int p = 0; p < 3; ++p) {
      const unsigned short* src =
          Wt3 + (size_t)(bn0 + rowS[p]) * 1024 + k0 + colS[p];
      __builtin_amdgcn_global_load_lds(
          (const __attribute__((address_space(1))) void*)src,
          (__attribute__((address_space(3))) void*)(&sB[buf][0] + (p * 512 + (wid << 6)) * 8),
          16, 0, 0);
    }
  };
  auto loadA = [&](int k0, int half, float4* v) {
    const float* base = x + (size_t)(bm0 + half * 128 + ar) * 1024 + k0 + acf;
#pragma unroll
    for (int i = 0; i < 4; ++i) v[i] = *(const float4*)(base + i * 4);
  };
  auto writeA = [&](int buf, int half, const float4* v) {
    us8 w0, w1;
    w0[0] = f2bf(v[0].x); w0[1] = f2bf(v[0].y);
    w0[2] = f2bf(v[0].z); w0[3] = f2bf(v[0].w);
    w0[4] = f2bf(v[1].x); w0[5] = f2bf(v[1].y);
    w0[6] = f2bf(v[1].z); w0[7] = f2bf(v[1].w);
    w1[0] = f2bf(v[2].x); w1[1] = f2bf(v[2].y);
    w1[2] = f2bf(v[2].z); w1[3] = f2bf(v[2].w);
    w1[4] = f2bf(v[3].x); w1[5] = f2bf(v[3].y);
    w1[6] = f2bf(v[3].z); w1[7] = f2bf(v[3].w);
    char* bp = (char*)&sX[buf][0] + (half * 128 + ar) * 128;
    *(us8*)(bp + (acb ^ asw)) = w0;
    *(us8*)(bp + ((acb + 16) ^ asw)) = w1;
  };
  auto rdX = [&](const unsigned short* base, int row, int k) -> bf16x8 {
    const int po = row * 128 + (((k * 32 + lk * 8) * 2) ^ ((row & 7) << 4));
    return *(const bf16x8*)((const char*)base + po);
  };

  // prologue: tile 0 staged, drained, barrier
  float4 xv0[4], xv1[4];
  loadA(0, 0, xv0);
  loadA(0, 1, xv1);
  stageB(0, 0);
  writeA(0, 0, xv0);
  writeA(0, 1, xv1);
  asm volatile("s_waitcnt vmcnt(0) lgkmcnt(0)" ::: "memory");
  __builtin_amdgcn_s_barrier();

  for (int kt = 0; kt < 16; ++kt) {
    const int cur = kt & 1, nxt = cur ^ 1;
    const bool pf = (kt + 1) < 16;
    const int k1 = (kt + 1) << 6;
    const unsigned short* sXc = &sX[cur][0];
    const unsigned short* sBc = &sB[cur][0];

    // issue next tile: A first (consumed at P2/P3 -> compiler waits leave B
    // in flight), B gload_lds last (longest flight, waited at boundary only)
    if (pf) {
      loadA(k1, 0, xv0);
      loadA(k1, 1, xv1);
      stageB(k1, nxt);
    }

    // B fragments for the whole iter (6 ds_read_b128)
    bf16x8 bb[3][2];
#pragma unroll
    for (int j = 0; j < 3; ++j)
#pragma unroll
      for (int k = 0; k < 2; ++k)
        bb[j][k] = rdX(sBc, wn * 48 + j * 16 + lr, k);

    // 4 phases: {2 A-frag-pairs ds_read -> 12 MFMA}, T14 writes at P2/P3
#pragma unroll
    for (int ph = 0; ph < 4; ++ph) {
      bf16x8 ax[2][2];
#pragma unroll
      for (int mm = 0; mm < 2; ++mm)
#pragma unroll
        for (int k = 0; k < 2; ++k)
          ax[mm][k] = rdX(sXc, wm * 128 + (ph * 2 + mm) * 16 + lr, k);

      if (ph == 2 && pf) writeA(nxt, 0, xv0);   // vmcnt wait auto (A0 only)
      if (ph == 3 && pf) writeA(nxt, 1, xv1);   // vmcnt wait auto (A1 only)

      __builtin_amdgcn_s_setprio(1);
#pragma unroll
      for (int mm = 0; mm < 2; ++mm)
#pragma unroll
        for (int j = 0; j < 3; ++j)
#pragma unroll
          for (int k = 0; k < 2; ++k)
            acc[ph * 2 + mm][j] = __builtin_amdgcn_mfma_f32_16x16x32_bf16(
                ax[mm][k], bb[j][k], acc[ph * 2 + mm][j], 0, 0, 0);
      __builtin_amdgcn_s_setprio(0);
    }

    // single per-iter boundary: my reads+writes retired, B(t+1) landed.
    asm volatile("s_waitcnt vmcnt(0) lgkmcnt(0)" ::: "memory");
    __builtin_amdgcn_s_barrier();
  }

  // epilogue. C/D layout: col=lane&15, row=(lane>>4)*4+reg [m89/m91].
  // np 16-col chunks are 16-aligned -> never straddle a 1024 boundary.
#pragma unroll
  for (int j = 0; j < 3; ++j) {
    const int np = bn0 + wn * 48 + j * 16 + lr;
    const int mat = np >> 10;
    const int nn = np & 1023;
    const float Ba = (mat == 0) ? ba[nn] : 0.0f;
#pragma unroll
    for (int m = 0; m < 8; ++m) {
      const int rbase = bm0 + wm * 128 + m * 16 + lk * 4;
#pragma unroll
      for (int q = 0; q < 4; ++q) {
        const size_t idx = (size_t)(rbase + q) * 1024 + nn;
        const float v = acc[m][j][q];
        if (mat == 0) {
          ya[idx] = f2bf(fmaxf(v + Ba, 0.0f));
        } else if (mat == 1) {
          pk16[idx * 2] = f2bf(v);          // ysh -> low u16
        } else {
          pk16[idx * 2 + 1] = f2bf(v);      // ysc -> high u16
        }
      }
    }
  }
}

// ---------------------------------------------------------------------------
// Kernel 3: causal Gaussian filter along t + combine, IN PLACE over d_out.
//   shift = filter(ysh)+bsh; scale = filter(ysc)+bsc; out = scale*ya + shift
// Each block owns one (batch, 32-col slice); halo pre-read into regs before a
// barrier so f32 overwrites never race bf16 reads. Static indexing (rule #20).
// ---------------------------------------------------------------------------
__global__ __launch_bounds__(512) void filter_combine(
    void* slab,                         // d_out: read packed u32, write f32
    const unsigned short* __restrict__ ya,
    const float* __restrict__ bshift, const float* __restrict__ bscale)
{
  const unsigned int* pk = (const unsigned int*)slab;
  float* outf = (float*)slab;

  const int tid = threadIdx.x;
  const int b = blockIdx.x >> 5;            // 8 batches
  const int n0 = (blockIdx.x & 31) << 5;    // 32 col-slices
  const int lane = tid & 63;
  const int w = tid >> 6;                   // 0..7
  const int seg = (w << 1) | (lane >> 5);   // 0..15, 64 t-rows each
  const int col = lane & 31;
  const int n = n0 + col;
  const int t0 = seg * 64;
  const size_t base = (size_t)b * 1024 * 1024 + n;  // + t*1024

  float g[16];
#pragma unroll
  for (int k = 0; k < 16; ++k) g[k] = __expf(-(float)(k * k) * 0.125f);
  float nfull = 0.f;
#pragma unroll
  for (int k = 0; k < 16; ++k) nfull += g[k];
  const float invf = 1.0f / nfull;

  // halo pre-read: rows t0-15 .. t0-1 (zeros at batch start)
  float psh[15], psc[15];
#pragma unroll
  for (int i = 0; i < 15; ++i) {
    float vs = 0.f, vc = 0.f;
    if (t0 > 0) {
      const unsigned int u = pk[base + (size_t)(t0 - 15 + i) * 1024];
      vs = bf2f(u & 0xffffu); vc = bf2f(u >> 16);
    }
    psh[i] = vs; psc[i] = vc;
  }
  __syncthreads();   // all halo reads complete before any f32 overwrite

  const float bs = bshift[n];
  const float bc = bscale[n];

  for (int c = 0; c < 4; ++c) {             // 4 chunks of 16 t-rows
    const int T = t0 + c * 16;
    unsigned int cu[16];
#pragma unroll
    for (int u = 0; u < 16; ++u) cu[u] = pk[base + (size_t)(T + u) * 1024];
    unsigned short yv[16];
#pragma unroll
    for (int u = 0; u < 16; ++u) yv[u] = ya[base + (size_t)(T + u) * 1024];
    float csh[16], csc[16];
#pragma unroll
    for (int u = 0; u < 16; ++u) {
      csh[u] = bf2f(cu[u] & 0xffffu);
      csc[u] = bf2f(cu[u] >> 16);
    }
#pragma unroll
    for (int u = 0; u < 16; ++u) {
      float fs = 0.f, fc = 0.f;
#pragma unroll
      for (int k = 0; k < 16; ++k) {
        const int d = u - k;
        const float vs = (d >= 0) ? csh[d] : psh[15 + d];
        const float vc = (d >= 0) ? csc[d] : psc[15 + d];
        fs = fmaf(g[k], vs, fs);
        fc = fmaf(g[k], vc, fc);
      }
      const int t = T + u;
      float inv = invf;
      if (t < 15) {                          // batch start: partial norm
        float s = 0.f;
#pragma unroll
        for (int k = 0; k < 16; ++k) s += (k <= t) ? g[k] : 0.f;
        inv = 1.0f / s;
      }
      const float shiftv = fs * inv + bs;
      const float scalev = fc * inv + bc;
      const float aff = bf2f((unsigned int)yv[u]);
      outf[base + (size_t)t * 1024] = scalev * aff + shiftv;
    }
#pragma unroll
    for (int i = 0; i < 15; ++i) { psh[i] = csh[i + 1]; psc[i] = csc[i + 1]; }
  }
}

// ---------------------------------------------------------------------------
// Workspace layout (22 MiB, proven safe; ws_size known to be in [22,38) MiB):
//   ya  : ws + 0        16 MiB (affine, bf16)
//   Wt3 : ws + 16 MiB    6 MiB (concat Wa^T|Wshift^T|Wscale^T, bf16)
// d_out doubles as the (ysh,ysc) bf16-pair slab before filter_combine
// overwrites it in place with the final f32 output.
// ---------------------------------------------------------------------------
extern "C" void kernel_launch(void* const* d_in, const int* in_sizes, int n_in,
                              void* d_out, int out_size, void* d_ws, size_t ws_size,
                              hipStream_t stream) {
  const float* x   = (const float*)d_in[0];
  const float* Wa  = (const float*)d_in[1];
  const float* ba  = (const float*)d_in[2];
  const float* Wsh = (const float*)d_in[3];
  const float* bsh = (const float*)d_in[4];
  const float* Wsc = (const float*)d_in[5];
  const float* bsc = (const float*)d_in[6];

  char* ws = (char*)d_ws;
  unsigned short* ya  = (unsigned short*)(ws);
  unsigned short* Wt3 = (unsigned short*)(ws + (16u << 20));

  hipLaunchKernelGGL(wconv, dim3(16, 16, 3), dim3(256), 0, stream,
                     Wa, Wsh, Wsc, Wt3);
  hipLaunchKernelGGL(gemm3, dim3(512), dim3(512), 0, stream,
                     x, Wt3, ba, ya, (unsigned short*)d_out);
  hipLaunchKernelGGL(filter_combine, dim3(256), dim3(512), 0, stream,
                     d_out, ya, bsh, bsc);
}

// Round 12
// 81.238 us; speedup vs baseline: 1.7839x; 1.7839x over previous
//
#include <hip/hip_runtime.h>
#include <stdint.h>

typedef __attribute__((ext_vector_type(8))) __bf16 bf16x8;
typedef __attribute__((ext_vector_type(4))) float f32x4;

__device__ __forceinline__ unsigned short f2bf(float f) {
  union { float f; unsigned int u; } v; v.f = f;
  unsigned int u = v.u;
  u = (u + 0x7FFFu + ((u >> 16) & 1u)) >> 16;   // RNE
  return (unsigned short)u;
}
__device__ __forceinline__ float bf2f(unsigned int u) {
  union { unsigned int u; float f; } v; v.u = u << 16;
  return v.f;
}

// ---------------------------------------------------------------------------
// Kernel 0: x (f32) -> xb (bf16), flat copy. Removes the f32->bf16 VALU chain
// from the GEMM K-loop (the structural diff vs m97 across R5-R11).
// ---------------------------------------------------------------------------
__global__ __launch_bounds__(256) void xconv(
    const float* __restrict__ x, unsigned short* __restrict__ xb)
{
  const size_t i = ((size_t)blockIdx.x * 256 + threadIdx.x) * 8;
  const float4 a = *(const float4*)(x + i);
  const float4 b = *(const float4*)(x + i + 4);
  ushort4 o0, o1;
  o0.x = f2bf(a.x); o0.y = f2bf(a.y); o0.z = f2bf(a.z); o0.w = f2bf(a.w);
  o1.x = f2bf(b.x); o1.y = f2bf(b.y); o1.z = f2bf(b.z); o1.w = f2bf(b.w);
  *(ushort4*)(xb + i) = o0;
  *(ushort4*)(xb + i + 4) = o1;
}

// ---------------------------------------------------------------------------
// Kernel 1: transpose + bf16-convert the three DxD weight matrices into one
// concatenated B' (3072 x 1024): Wt3[mat*1024 + n][k] = (bf16) W_mat[k][n].
// ---------------------------------------------------------------------------
__global__ __launch_bounds__(256) void wconv(
    const float* __restrict__ Wa, const float* __restrict__ Wsh,
    const float* __restrict__ Wsc, unsigned short* __restrict__ Wt3)
{
  const float* W;
  if (blockIdx.z == 0)      W = Wa;
  else if (blockIdx.z == 1) W = Wsh;
  else                      W = Wsc;
  unsigned short* O = Wt3 + (size_t)blockIdx.z * 1024 * 1024;
  const int k0 = blockIdx.x * 64;
  const int n0 = blockIdx.y * 64;
  __shared__ float t[64][65];
  const int r = threadIdx.x >> 4;
  const int c4 = threadIdx.x & 15;
#pragma unroll
  for (int i = 0; i < 4; ++i) {
    const int row = r + i * 16;
    const float4 v = *(const float4*)(W + (size_t)(k0 + row) * 1024 + n0 + c4 * 4);
    t[row][c4 * 4 + 0] = v.x; t[row][c4 * 4 + 1] = v.y;
    t[row][c4 * 4 + 2] = v.z; t[row][c4 * 4 + 3] = v.w;
  }
  __syncthreads();
#pragma unroll
  for (int i = 0; i < 4; ++i) {
    const int nr = r + i * 16;
    ushort4 o;
    o.x = f2bf(t[c4 * 4 + 0][nr]);
    o.y = f2bf(t[c4 * 4 + 1][nr]);
    o.z = f2bf(t[c4 * 4 + 2][nr]);
    o.w = f2bf(t[c4 * 4 + 3][nr]);
    *(ushort4*)(O + (size_t)(n0 + nr) * 1024 + k0 + c4 * 4) = o;
  }
}

// ---------------------------------------------------------------------------
// Kernel 2: fused triple GEMM + IN-KERNEL Gaussian filter + combine.
// R11 post-mortem: spill (WRITE_SIZE 55->110MB). R5-R11 invariant: in-loop
// f32->bf16 A-staging chain in front of every barrier. R12 = m97-exact
// staging: BOTH operands via global_load_lds from bf16 (xb prepass), zero
// in-loop VALU. Fused 3-acc tile BM=128 BN=64 BK=64, 4 waves (wave 64x32,
// acc 96 + 16 halo), single-buffer 2-barrier m97 loop, grid 1024 (= 2 exact
// rounds at 2 blocks/CU). A 16-row halo of ysh/ysc lets the epilogue apply
// the causal Gaussian filter + combine locally: dump acc->LDS bf16, filter
// along t per column strip, write final f32 to d_out. ya/pk/filter_combine
// kernels eliminated (-80 MB traffic). firstblk == (xcd==0): halo zeroed,
// partial norm. Swizzle swz(row)=(row&7)<<4 on gload_lds SOURCE + ds_read
// (rule #21, proven pair from R9).
// ---------------------------------------------------------------------------
__global__ __launch_bounds__(256, 2) void gemm_all(
    const unsigned short* __restrict__ xb, const unsigned short* __restrict__ Wt3,
    const float* __restrict__ ba, const float* __restrict__ bsh,
    const float* __restrict__ bsc, float* __restrict__ out)
{
  // LDS union: staging {sX 20480 | sB 24576} = 45056; epilogue
  // {ysh 18688 | ysc 18688 | aff 16640} = 54016.  54016*2 = 108 KB/CU.
  __shared__ __attribute__((aligned(16))) char lds[54016];
  unsigned short* sX = (unsigned short*)lds;              // 160 rows x 128 B
  unsigned short* sB = (unsigned short*)(lds + 20480);    // 3 x 64 rows x 128 B
  unsigned short* ysh_l = (unsigned short*)lds;           // [64 col][146 row]
  unsigned short* ysc_l = (unsigned short*)(lds + 18688);
  unsigned short* aff_l = (unsigned short*)(lds + 37376); // [64 col][130 row]

  const int tid = threadIdx.x;
  const int lane = tid & 63;
  const int wid = tid >> 6;      // 0..3
  const int wm = wid >> 1;       // 0..1 (M half: 64 rows)
  const int wn = wid & 1;        // 0..1 (N half: 32 cols)
  const int lr = lane & 15;
  const int lk = lane >> 4;

  // 1024 blocks = 64 M x 16 N. XCD-ownership remap (R7-proven).
  const int bid = blockIdx.x;
  const int xcd = bid & 7;
  const int rr_ = bid >> 3;          // 0..127
  const int ntl = rr_ & 15;
  const int mg  = rr_ >> 4;          // 0..7
  const int bm0 = (xcd + (mg << 3)) * 128;
  const int bn0 = ntl * 64;
  const bool first = (xcd == 0);     // bm0 % 1024 == 0 exactly

  f32x4 acc[3][4][2];                // [mat][m][jj] = 96 regs
  f32x4 hacc[2][2];                  // halo: [mat-1][jj] = 16 regs
  const f32x4 z = {0.f, 0.f, 0.f, 0.f};
#pragma unroll
  for (int a = 0; a < 3; ++a)
#pragma unroll
    for (int m = 0; m < 4; ++m)
#pragma unroll
      for (int j = 0; j < 2; ++j) acc[a][m][j] = z;
#pragma unroll
  for (int a = 0; a < 2; ++a)
#pragma unroll
    for (int j = 0; j < 2; ++j) hacc[a][j] = z;

  auto stage = [&](int k0) {
    // sX: 5 rounds of 4 KB. LDS rows: 0..15 halo (bm0-16..bm0-1),
    // 16..143 main, 144..159 waste (dummy row bm0).
#pragma unroll
    for (int p = 0; p < 5; ++p) {
      const int po = (p * 256 + tid) * 16;
      const int row = po >> 7;
      const int lo = po ^ ((row & 7) << 4);
      const int colu = (lo & 127) >> 1;
      int rel = row - 16;
      if (rel < 0 && first) rel = 0;       // firstblk halo -> dummy (zeroed later)
      if (rel > 127) rel = 0;              // waste rows -> dummy
      const unsigned short* src = xb + (size_t)(bm0 + rel) * 1024 + k0 + colu;
      __builtin_amdgcn_global_load_lds(
          (const __attribute__((address_space(1))) void*)src,
          (__attribute__((address_space(3))) void*)(sX + (p * 256 + (wid << 6)) * 8),
          16, 0, 0);
    }
    // sB: 3 mats x 2 rounds of 4 KB
#pragma unroll
    for (int mat = 0; mat < 3; ++mat)
#pragma unroll
      for (int p = 0; p < 2; ++p) {
        const int po = (p * 256 + tid) * 16;
        const int row = po >> 7;
        const int lo = po ^ ((row & 7) << 4);
        const int colu = (lo & 127) >> 1;
        const unsigned short* src =
            Wt3 + ((size_t)mat << 20) + (size_t)(bn0 + row) * 1024 + k0 + colu;
        __builtin_amdgcn_global_load_lds(
            (const __attribute__((address_space(1))) void*)src,
            (__attribute__((address_space(3))) void*)(sB + mat * 4096 + (p * 256 + (wid << 6)) * 8),
            16, 0, 0);
      }
  };
  auto rd = [&](const unsigned short* base, int row, int s) -> bf16x8 {
    const int po = row * 128 + (((s * 32 + lk * 8) * 2) ^ ((row & 7) << 4));
    return *(const bf16x8*)((const char*)base + po);
  };

  stage(0);

  for (int kt = 0; kt < 16; ++kt) {
    __syncthreads();   // drains vmcnt+lgkm: tile ready

#pragma unroll
    for (int s = 0; s < 2; ++s) {
      bf16x8 ax[4], bb[3][2], hax;
#pragma unroll
      for (int m = 0; m < 4; ++m)
        ax[m] = rd(sX, 16 + wm * 64 + m * 16 + lr, s);
#pragma unroll
      for (int mat = 0; mat < 3; ++mat)
#pragma unroll
        for (int jj = 0; jj < 2; ++jj)
          bb[mat][jj] = rd(sB + mat * 4096, wn * 32 + jj * 16 + lr, s);
      if (wm == 0) hax = rd(sX, lr, s);

      __builtin_amdgcn_s_setprio(1);
#pragma unroll
      for (int m = 0; m < 4; ++m)
#pragma unroll
        for (int mat = 0; mat < 3; ++mat)
#pragma unroll
          for (int jj = 0; jj < 2; ++jj)
            acc[mat][m][jj] = __builtin_amdgcn_mfma_f32_16x16x32_bf16(
                ax[m], bb[mat][jj], acc[mat][m][jj], 0, 0, 0);
      if (wm == 0) {
#pragma unroll
        for (int mat = 1; mat < 3; ++mat)
#pragma unroll
          for (int jj = 0; jj < 2; ++jj)
            hacc[mat - 1][jj] = __builtin_amdgcn_mfma_f32_16x16x32_bf16(
                hax, bb[mat][jj], hacc[mat - 1][jj], 0, 0, 0);
      }
      __builtin_amdgcn_s_setprio(0);
    }

    __syncthreads();   // all reads done; LDS reusable
    if (kt + 1 < 16) stage((kt + 1) * 64);
  }

  // ---- epilogue: dump acc -> LDS (bf16), filter along t, combine, write ----
  // C/D layout: col=lane&15, row=(lane>>4)*4+reg [m89/m91]
#pragma unroll
  for (int jj = 0; jj < 2; ++jj) {
    const int nn = wn * 32 + jj * 16 + lr;          // 0..63
    const float Ba = ba[bn0 + nn];
#pragma unroll
    for (int m = 0; m < 4; ++m)
#pragma unroll
      for (int q = 0; q < 4; ++q) {
        const int rowL = wm * 64 + m * 16 + lk * 4 + q;   // 0..127
        aff_l[nn * 130 + rowL] = f2bf(fmaxf(acc[0][m][jj][q] + Ba, 0.0f));
        ysh_l[nn * 146 + 15 + rowL] = f2bf(acc[1][m][jj][q]);
        ysc_l[nn * 146 + 15 + rowL] = f2bf(acc[2][m][jj][q]);
      }
    if (wm == 0) {
#pragma unroll
      for (int q = 0; q < 4; ++q) {
        const int hr = lk * 4 + q;          // 0..15 <-> global bm0-16+hr
        if (hr > 0) {                       // need bm0-15..bm0-1 -> idx 0..14
          ysh_l[nn * 146 + hr - 1] = f2bf(hacc[0][jj][q]);
          ysc_l[nn * 146 + hr - 1] = f2bf(hacc[1][jj][q]);
        }
      }
    }
  }
  __syncthreads();
  if (first) {     // batch start: halo is zeros
    for (int i = tid; i < 64 * 15; i += 256) {
      const int nn = i / 15, rw = i % 15;
      ysh_l[nn * 146 + rw] = 0;
      ysc_l[nn * 146 + rw] = 0;
    }
  }
  __syncthreads();

  // filter + combine: thread owns (col nn, 32 rows)
  {
    const int nn = tid & 63;
    const int t0 = (tid >> 6) * 32;
    float g[16];
#pragma unroll
    for (int k = 0; k < 16; ++k) g[k] = __expf(-(float)(k * k) * 0.125f);
    float nfull = 0.f;
#pragma unroll
    for (int k = 0; k < 16; ++k) nfull += g[k];
    const float invf = 1.0f / nfull;
    const float bs = bsh[bn0 + nn];
    const float bc = bsc[bn0 + nn];

    float psh[15], psc[15];
#pragma unroll
    for (int i = 0; i < 15; ++i) {          // window rows t0-15..t0-1 -> idx t0+i
      psh[i] = bf2f(ysh_l[nn * 146 + t0 + i]);
      psc[i] = bf2f(ysc_l[nn * 146 + t0 + i]);
    }

    for (int c = 0; c < 2; ++c) {           // 2 chunks of 16 rows
      const int T = t0 + c * 16;
      float csh[16], csc[16], av[16];
#pragma unroll
      for (int u = 0; u < 16; ++u) {
        csh[u] = bf2f(ysh_l[nn * 146 + 15 + T + u]);
        csc[u] = bf2f(ysc_l[nn * 146 + 15 + T + u]);
        av[u]  = bf2f(aff_l[nn * 130 + T + u]);
      }
#pragma unroll
      for (int u = 0; u < 16; ++u) {
        float fs = 0.f, fc = 0.f;
#pragma unroll
        for (int k = 0; k < 16; ++k) {
          const int d = u - k;
          const float vs = (d >= 0) ? csh[d] : psh[15 + d];
          const float vc = (d >= 0) ? csc[d] : psc[15 + d];
          fs = fmaf(g[k], vs, fs);
          fc = fmaf(g[k], vc, fc);
        }
        float inv = invf;
        if (first && (T + u) < 15) {        // partial norm at batch start
          float sum = 0.f;
#pragma unroll
          for (int k = 0; k < 16; ++k) sum += (k <= T + u) ? g[k] : 0.f;
          inv = 1.0f / sum;
        }
        out[(size_t)(bm0 + T + u) * 1024 + bn0 + nn] =
            (fc * inv + bc) * av[u] + (fs * inv + bs);
      }
#pragma unroll
      for (int i = 0; i < 15; ++i) { psh[i] = csh[i + 1]; psc[i] = csc[i + 1]; }
    }
  }
}

// ---------------------------------------------------------------------------
// Workspace layout (22 MiB, proven safe):
//   xb  : ws + 0        16 MiB (x as bf16)
//   Wt3 : ws + 16 MiB    6 MiB (concat Wa^T|Wshift^T|Wscale^T, bf16)
// d_out is written ONCE by gemm_all (final f32) — no intermediate slab.
// ---------------------------------------------------------------------------
extern "C" void kernel_launch(void* const* d_in, const int* in_sizes, int n_in,
                              void* d_out, int out_size, void* d_ws, size_t ws_size,
                              hipStream_t stream) {
  const float* x   = (const float*)d_in[0];
  const float* Wa  = (const float*)d_in[1];
  const float* ba  = (const float*)d_in[2];
  const float* Wsh = (const float*)d_in[3];
  const float* bsh = (const float*)d_in[4];
  const float* Wsc = (const float*)d_in[5];
  const float* bsc = (const float*)d_in[6];
  float* out = (float*)d_out;

  char* ws = (char*)d_ws;
  unsigned short* xb  = (unsigned short*)(ws);
  unsigned short* Wt3 = (unsigned short*)(ws + (16u << 20));

  hipLaunchKernelGGL(xconv, dim3(4096), dim3(256), 0, stream, x, xb);
  hipLaunchKernelGGL(wconv, dim3(16, 16, 3), dim3(256), 0, stream,
                     Wa, Wsh, Wsc, Wt3);
  hipLaunchKernelGGL(gemm_all, dim3(1024), dim3(256), 0, stream,
                     xb, Wt3, ba, bsh, bsc, out);
}

// Round 13
// 79.335 us; speedup vs baseline: 1.8267x; 1.0240x over previous
//
#include <hip/hip_runtime.h>
#include <stdint.h>

typedef __attribute__((ext_vector_type(8))) __bf16 bf16x8;
typedef __attribute__((ext_vector_type(4))) float f32x4;

__device__ __forceinline__ unsigned short f2bf(float f) {
  union { float f; unsigned int u; } v; v.f = f;
  unsigned int u = v.u;
  u = (u + 0x7FFFu + ((u >> 16) & 1u)) >> 16;   // RNE
  return (unsigned short)u;
}
__device__ __forceinline__ float bf2f(unsigned int u) {
  union { unsigned int u; float f; } v; v.u = u << 16;
  return v.f;
}

// ---------------------------------------------------------------------------
// Kernel 1 (prep): fused  [bid < 4096] x f32 -> bf16 flat copy
//                         [bid >= 4096] W transpose+convert into Wt3 concat.
// ---------------------------------------------------------------------------
__global__ __launch_bounds__(256) void prep(
    const float* __restrict__ x, unsigned short* __restrict__ xb,
    const float* __restrict__ Wa, const float* __restrict__ Wsh,
    const float* __restrict__ Wsc, unsigned short* __restrict__ Wt3)
{
  __shared__ float t[64][65];
  int bid = blockIdx.x;
  if (bid < 4096) {
    const size_t i = ((size_t)bid * 256 + threadIdx.x) * 8;
    const float4 a = *(const float4*)(x + i);
    const float4 b = *(const float4*)(x + i + 4);
    ushort4 o0, o1;
    o0.x = f2bf(a.x); o0.y = f2bf(a.y); o0.z = f2bf(a.z); o0.w = f2bf(a.w);
    o1.x = f2bf(b.x); o1.y = f2bf(b.y); o1.z = f2bf(b.z); o1.w = f2bf(b.w);
    *(ushort4*)(xb + i) = o0;
    *(ushort4*)(xb + i + 4) = o1;
    return;
  }
  bid -= 4096;                       // 768 blocks: 16 x 16 x 3
  const int z  = bid >> 8;           // mat
  const int yy = (bid >> 4) & 15;    // n tile
  const int xx = bid & 15;           // k tile
  const float* W = (z == 0) ? Wa : (z == 1) ? Wsh : Wsc;
  unsigned short* O = Wt3 + ((size_t)z << 20);
  const int k0 = xx * 64;
  const int n0 = yy * 64;
  const int r = threadIdx.x >> 4;
  const int c4 = threadIdx.x & 15;
#pragma unroll
  for (int i = 0; i < 4; ++i) {
    const int row = r + i * 16;
    const float4 v = *(const float4*)(W + (size_t)(k0 + row) * 1024 + n0 + c4 * 4);
    t[row][c4 * 4 + 0] = v.x; t[row][c4 * 4 + 1] = v.y;
    t[row][c4 * 4 + 2] = v.z; t[row][c4 * 4 + 3] = v.w;
  }
  __syncthreads();
#pragma unroll
  for (int i = 0; i < 4; ++i) {
    const int nr = r + i * 16;
    ushort4 o;
    o.x = f2bf(t[c4 * 4 + 0][nr]);
    o.y = f2bf(t[c4 * 4 + 1][nr]);
    o.z = f2bf(t[c4 * 4 + 2][nr]);
    o.w = f2bf(t[c4 * 4 + 3][nr]);
    *(ushort4*)(O + (size_t)(n0 + nr) * 1024 + k0 + c4 * 4) = o;
  }
}

// ---------------------------------------------------------------------------
// Kernel 2: fused triple GEMM + in-kernel Gaussian filter + combine.
// R12 post-mortem: m97-exact staging broke the plateau (117->81us, ~750 TF
// effective) but the single-buffer loop still serializes stage -> full
// vmcnt(0) drain -> compute per K-step (MfmaUtil 23%).
// R13 = T3-minimum counted-vmcnt pipeline (now viable: no in-loop VALU
// staging -> no spill risk; pure gload_lds -> simple count):
//   per iter: stage(t+1,next) ; s_waitcnt vmcnt(8|7) ; s_barrier ;
//             ds_read+MFMA(setprio) ; lgkmcnt(0) ; s_barrier ; swap.
// vmcnt never 0 in-loop (T4, m218/m248). Waves 0-1 issue 8 gload_lds per
// stage (4 sX + 1 halo + 3 sB), waves 2-7 issue 7 -> wave-uniform branch.
// asm("" ::: "memory") after each raw barrier fences LDS-read hoisting.
// Geometry: BM=256(+16 halo rows) BN=64 x 3 mats, 512 thr (8 waves 4Mx2N,
// wave 64x32, acc 96+16 regs). LDS: dbuf 116 KB / epilogue union 103 KB ->
// 1 block/CU (m201 operating point: intra-block overlap, not cross-block).
// Swizzle swz(row)=(row&7)<<4 on gload_lds SOURCE + ds_read (rule #21).
// first = (bm0%1024==0): halo zeroed, partial norm (batch boundary).
// ---------------------------------------------------------------------------
__global__ __launch_bounds__(512, 2) void gemm_all(
    const unsigned short* __restrict__ xb, const unsigned short* __restrict__ Wt3,
    const float* __restrict__ ba, const float* __restrict__ bsh,
    const float* __restrict__ bsc, float* __restrict__ out)
{
  // staging: sX0 @0 (34816 = 272 rows x 128B), sX1 @34816,
  //          sB0 @69632 (24576 = 3 x 64 x 128B), sB1 @94208  -> 118784 B
  // epilogue union: ysh [64][274] @0, ysc @35072, aff [64][258] @70144
  __shared__ __attribute__((aligned(16))) char lds[118784];
  unsigned short* const sX0 = (unsigned short*)lds;
  unsigned short* const sX1 = (unsigned short*)(lds + 34816);
  unsigned short* const sB0 = (unsigned short*)(lds + 69632);
  unsigned short* const sB1 = (unsigned short*)(lds + 94208);
  unsigned short* const ysh_l = (unsigned short*)lds;
  unsigned short* const ysc_l = (unsigned short*)(lds + 35072);
  unsigned short* const aff_l = (unsigned short*)(lds + 70144);

  const int tid = threadIdx.x;
  const int lane = tid & 63;
  const int wid = tid >> 6;      // 0..7
  const int wm = wid >> 1;       // 0..3 (M quarter: 64 rows)
  const int wn = wid & 1;        // 0..1 (N half: 32 cols)
  const int lr = lane & 15;
  const int lk = lane >> 4;

  // 512 blocks = 32 M x 16 N. XCD-ownership remap (R7-proven).
  const int bid = blockIdx.x;
  const int xcd = bid & 7;
  const int rr_ = bid >> 3;          // 0..63
  const int ntl = rr_ & 15;
  const int mg  = rr_ >> 4;          // 0..3
  const int bm0 = (xcd + (mg << 3)) * 256;
  const int bn0 = ntl * 64;
  const bool first = ((bm0 & 1023) == 0);   // batch boundary above this tile

  f32x4 acc[3][4][2];                // [mat][m][jj] = 96 regs
  f32x4 hacc[2][2];                  // halo rows (wm==0 waves): 16 regs
  const f32x4 z = {0.f, 0.f, 0.f, 0.f};
#pragma unroll
  for (int a = 0; a < 3; ++a)
#pragma unroll
    for (int m = 0; m < 4; ++m)
#pragma unroll
      for (int j = 0; j < 2; ++j) acc[a][m][j] = z;
#pragma unroll
  for (int a = 0; a < 2; ++a)
#pragma unroll
    for (int j = 0; j < 2; ++j) hacc[a][j] = z;

  // stage one K-tile (BK=64): sX rows 0..255 = bm0+row, rows 256..271 = halo
  // (bm0-16..bm0-1; dummy row bm0 when first). All swizzle on global SOURCE.
  auto stage = [&](int k0, unsigned short* dX, unsigned short* dB) {
#pragma unroll
    for (int p = 0; p < 4; ++p) {                 // main X: 4 x 8 KB rounds
      const int po = (p * 512 + tid) * 16;
      const int row = po >> 7;                    // 0..255
      const int lo = po ^ ((row & 7) << 4);
      const int colu = (lo & 127) >> 1;
      const unsigned short* src = xb + (size_t)(bm0 + row) * 1024 + k0 + colu;
      __builtin_amdgcn_global_load_lds(
          (const __attribute__((address_space(1))) void*)src,
          (__attribute__((address_space(3))) void*)(dX + (p * 512 + (wid << 6)) * 8),
          16, 0, 0);
    }
    if (tid < 128) {                              // halo X: waves 0-1 only
      const int po = (2048 + tid) * 16;
      const int row = po >> 7;                    // 256..271
      const int lo = po ^ ((row & 7) << 4);
      const int colu = (lo & 127) >> 1;
      int grow = bm0 - 16 + (row - 256);
      if (first) grow = bm0;                      // dummy; epilogue zeroes halo
      const unsigned short* src = xb + (size_t)grow * 1024 + k0 + colu;
      __builtin_amdgcn_global_load_lds(
          (const __attribute__((address_space(1))) void*)src,
          (__attribute__((address_space(3))) void*)(dX + (2048 + (wid << 6)) * 8),
          16, 0, 0);
    }
#pragma unroll
    for (int mat = 0; mat < 3; ++mat) {           // B: 3 x 8 KB rounds
      const int po = tid * 16;
      const int row = po >> 7;                    // 0..63
      const int lo = po ^ ((row & 7) << 4);
      const int colu = (lo & 127) >> 1;
      const unsigned short* src =
          Wt3 + ((size_t)mat << 20) + (size_t)(bn0 + row) * 1024 + k0 + colu;
      __builtin_amdgcn_global_load_lds(
          (const __attribute__((address_space(1))) void*)src,
          (__attribute__((address_space(3))) void*)(dB + mat * 4096 + (wid << 6) * 8),
          16, 0, 0);
    }
  };
  auto rd = [&](const unsigned short* base, int row, int s) -> bf16x8 {
    const int po = row * 128 + (((s * 32 + lk * 8) * 2) ^ ((row & 7) << 4));
    return *(const bf16x8*)((const char*)base + po);
  };

  stage(0, sX0, sB0);
  unsigned short *sXc = sX0, *sBc = sB0, *sXn = sX1, *sBn = sB1;

  for (int kt = 0; kt < 16; ++kt) {
    if (kt + 1 < 16) stage((kt + 1) * 64, sXn, sBn);   // issue next tile NOW

    // T4 counted wait: tile kt's loads landed; tile kt+1's stay in flight.
    if (kt + 1 < 16) {
      if (wid < 2) asm volatile("s_waitcnt vmcnt(8)" ::: "memory");
      else         asm volatile("s_waitcnt vmcnt(7)" ::: "memory");
    } else {
      asm volatile("s_waitcnt vmcnt(0)" ::: "memory");
    }
    __builtin_amdgcn_s_barrier();                      // tile kt ready (all waves)
    asm volatile("" ::: "memory");                     // no LDS read hoists above

#pragma unroll
    for (int s = 0; s < 2; ++s) {
      bf16x8 ax[4], bb[3][2], hax;
#pragma unroll
      for (int m = 0; m < 4; ++m)
        ax[m] = rd(sXc, wm * 64 + m * 16 + lr, s);
#pragma unroll
      for (int mat = 0; mat < 3; ++mat)
#pragma unroll
        for (int jj = 0; jj < 2; ++jj)
          bb[mat][jj] = rd(sBc + mat * 4096, wn * 32 + jj * 16 + lr, s);
      if (wm == 0) hax = rd(sXc, 256 + lr, s);

      __builtin_amdgcn_s_setprio(1);
#pragma unroll
      for (int m = 0; m < 4; ++m)
#pragma unroll
        for (int mat = 0; mat < 3; ++mat)
#pragma unroll
          for (int jj = 0; jj < 2; ++jj)
            acc[mat][m][jj] = __builtin_amdgcn_mfma_f32_16x16x32_bf16(
                ax[m], bb[mat][jj], acc[mat][m][jj], 0, 0, 0);
      if (wm == 0) {
#pragma unroll
        for (int mat = 1; mat < 3; ++mat)
#pragma unroll
          for (int jj = 0; jj < 2; ++jj)
            hacc[mat - 1][jj] = __builtin_amdgcn_mfma_f32_16x16x32_bf16(
                hax, bb[mat][jj], hacc[mat - 1][jj], 0, 0, 0);
      }
      __builtin_amdgcn_s_setprio(0);
    }

    asm volatile("s_waitcnt lgkmcnt(0)" ::: "memory"); // my slot reads done
    __builtin_amdgcn_s_barrier();                      // slot reusable
    asm volatile("" ::: "memory");                     // stage can't sink above

    unsigned short* t1 = sXc; sXc = sXn; sXn = t1;
    unsigned short* t2 = sBc; sBc = sBn; sBn = t2;
  }

  // ---- epilogue: dump acc -> LDS bf16, Gaussian filter along t, combine ----
  // C/D layout: col=lane&15, row=(lane>>4)*4+reg [m89/m91]
#pragma unroll
  for (int jj = 0; jj < 2; ++jj) {
    const int nn = wn * 32 + jj * 16 + lr;          // 0..63
    const float Ba = ba[bn0 + nn];
#pragma unroll
    for (int m = 0; m < 4; ++m)
#pragma unroll
      for (int q = 0; q < 4; ++q) {
        const int rowL = wm * 64 + m * 16 + lk * 4 + q;   // 0..255
        aff_l[nn * 258 + rowL] = f2bf(fmaxf(acc[0][m][jj][q] + Ba, 0.0f));
        ysh_l[nn * 274 + 15 + rowL] = f2bf(acc[1][m][jj][q]);
        ysc_l[nn * 274 + 15 + rowL] = f2bf(acc[2][m][jj][q]);
      }
    if (wm == 0) {
#pragma unroll
      for (int q = 0; q < 4; ++q) {
        const int hr = lk * 4 + q;          // 0..15 <-> global bm0-16+hr
        if (hr > 0) {                       // entries 0..14 = bm0-15..bm0-1
          ysh_l[nn * 274 + hr - 1] = f2bf(hacc[0][jj][q]);
          ysc_l[nn * 274 + hr - 1] = f2bf(hacc[1][jj][q]);
        }
      }
    }
  }
  __syncthreads();
  if (first) {     // batch start: halo is zeros
    for (int i = tid; i < 64 * 15; i += 512) {
      const int nn = i / 15, rw = i % 15;
      ysh_l[nn * 274 + rw] = 0;
      ysc_l[nn * 274 + rw] = 0;
    }
  }
  __syncthreads();

  // filter + combine: thread owns (col nn, 32 rows)
  {
    const int nn = tid & 63;
    const int t0 = (tid >> 6) * 32;                 // 0..224
    float g[16];
#pragma unroll
    for (int k = 0; k < 16; ++k) g[k] = __expf(-(float)(k * k) * 0.125f);
    float nfull = 0.f;
#pragma unroll
    for (int k = 0; k < 16; ++k) nfull += g[k];
    const float invf = 1.0f / nfull;
    const float bs = bsh[bn0 + nn];
    const float bc = bsc[bn0 + nn];

    float psh[15], psc[15];
#pragma unroll
    for (int i = 0; i < 15; ++i) {                  // rows t0-15..t0-1
      psh[i] = bf2f(ysh_l[nn * 274 + t0 + i]);
      psc[i] = bf2f(ysc_l[nn * 274 + t0 + i]);
    }

    for (int c = 0; c < 2; ++c) {                   // 2 chunks of 16 rows
      const int T = t0 + c * 16;
      float csh[16], csc[16], av[16];
#pragma unroll
      for (int u = 0; u < 16; ++u) {
        csh[u] = bf2f(ysh_l[nn * 274 + 15 + T + u]);
        csc[u] = bf2f(ysc_l[nn * 274 + 15 + T + u]);
        av[u]  = bf2f(aff_l[nn * 258 + T + u]);
      }
#pragma unroll
      for (int u = 0; u < 16; ++u) {
        float fs = 0.f, fc = 0.f;
#pragma unroll
        for (int k = 0; k < 16; ++k) {
          const int d = u - k;
          const float vs = (d >= 0) ? csh[d] : psh[15 + d];
          const float vc = (d >= 0) ? csc[d] : psc[15 + d];
          fs = fmaf(g[k], vs, fs);
          fc = fmaf(g[k], vc, fc);
        }
        float inv = invf;
        if (first && (T + u) < 15) {                // partial norm at batch start
          float sum = 0.f;
#pragma unroll
          for (int k = 0; k < 16; ++k) sum += (k <= T + u) ? g[k] : 0.f;
          inv = 1.0f / sum;
        }
        out[(size_t)(bm0 + T + u) * 1024 + bn0 + nn] =
            (fc * inv + bc) * av[u] + (fs * inv + bs);
      }
#pragma unroll
      for (int i = 0; i < 15; ++i) { psh[i] = csh[i + 1]; psc[i] = csc[i + 1]; }
    }
  }
}

// ---------------------------------------------------------------------------
// Workspace layout (22 MiB, proven safe):
//   xb  : ws + 0        16 MiB (x as bf16)
//   Wt3 : ws + 16 MiB    6 MiB (concat Wa^T|Wshift^T|Wscale^T, bf16)
// d_out is written ONCE by gemm_all (final f32).
// ---------------------------------------------------------------------------
extern "C" void kernel_launch(void* const* d_in, const int* in_sizes, int n_in,
                              void* d_out, int out_size, void* d_ws, size_t ws_size,
                              hipStream_t stream) {
  const float* x   = (const float*)d_in[0];
  const float* Wa  = (const float*)d_in[1];
  const float* ba  = (const float*)d_in[2];
  const float* Wsh = (const float*)d_in[3];
  const float* bsh = (const float*)d_in[4];
  const float* Wsc = (const float*)d_in[5];
  const float* bsc = (const float*)d_in[6];
  float* out = (float*)d_out;

  char* ws = (char*)d_ws;
  unsigned short* xb  = (unsigned short*)(ws);
  unsigned short* Wt3 = (unsigned short*)(ws + (16u << 20));

  hipLaunchKernelGGL(prep, dim3(4096 + 768), dim3(256), 0, stream,
                     x, xb, Wa, Wsh, Wsc, Wt3);
  hipLaunchKernelGGL(gemm_all, dim3(512), dim3(512), 0, stream,
                     xb, Wt3, ba, bsh, bsc, out);
}